// Round 10
// baseline (132.920 us; speedup 1.0000x reference)
//
#include <hip/hip_runtime.h>
#include <hip/hip_bf16.h>

// CRF log-likelihood, MI355X. SEQ=512, B=1024, T=48.
// One wave per batch chain (1024 waves). Serial matvec q = p @ E done by MFMA
// (6 x mfma_f32_16x16x32_bf16 per step), state kept in A-fragment layout.
// Per-step transpose C->A via 10 ds_bpermute + cvt_pk (no LDS round-trip).
// Linear domain with per-group exact power-of-2 renorm folded into the
// emission multiply. Numerator chunk-parallel as before. Emissions
// double-buffered in LDS via global_load_lds. Fragment layouts HW-verified
// in round 5 (A: row=l&15,k=(l>>4)*8+e; B: k=(l>>4)*8+e,col=l&15;
// C: row0 = lanes 0-15 reg0; B rows k>=48 zeroed so A-gather junk annihilates).

constexpr int SEQ = 512, BN = 1024, TT = 48;
constexpr int CH = 64, NCH = SEQ / CH;
#define LOG2E 1.44269504088896340736f
#define LN2   0.69314718055994530942f

typedef float f32x4 __attribute__((ext_vector_type(4)));
typedef short s16x8 __attribute__((ext_vector_type(8)));
typedef int   s32x4 __attribute__((ext_vector_type(4)));
typedef unsigned short u16;

__device__ __forceinline__ float fexp2(float x){ return __builtin_amdgcn_exp2f(x); }
__device__ __forceinline__ float flog2(float x){ return __builtin_amdgcn_logf(x); }
__device__ __forceinline__ float rlane0(float v){
    return __int_as_float(__builtin_amdgcn_readlane(__float_as_int(v), 0));
}
__device__ __forceinline__ int bperm(int addr, int src){
    return __builtin_amdgcn_ds_bpermute(addr, src);
}
__device__ __forceinline__ float bpermf(int addr, float src){
    return __int_as_float(bperm(addr, __float_as_int(src)));
}
__device__ __forceinline__ int cvtpk(float lo, float hi){
    int r;
    asm("v_cvt_pk_bf16_f32 %0, %1, %2" : "=v"(r) : "v"(lo), "v"(hi));
    return r;
}
__device__ __forceinline__ u16 f2bf(float f){
    __hip_bfloat16 h = __float2bfloat16(f);
    return __builtin_bit_cast(u16, h);
}
__device__ __forceinline__ f32x4 MFMA(s32x4 a, s32x4 b, f32x4 c){
    return __builtin_amdgcn_mfma_f32_16x16x32_bf16(
        __builtin_bit_cast(s16x8, a), __builtin_bit_cast(s16x8, b), c, 0, 0, 0);
}

__global__ __launch_bounds__(64, 1) void crf_fwd(
    const float* __restrict__ emis, const int* __restrict__ tags,
    const int* __restrict__ mask, const float* __restrict__ start_t,
    const float* __restrict__ end_t, const float* __restrict__ trans,
    float* __restrict__ ws)
{
    __shared__ float ltr[TT * TT];
    __shared__ __align__(16) float ebuf[2][CH * TT];  // 2 x 12 KB
    __shared__ float stb[64], enb[64];

    const int lane = threadIdx.x;
    const int b = blockIdx.x;
    const bool jv = (lane < TT);
    const int jc = jv ? lane : (TT - 1);

    // staging offsets (16B per lane per instr)
    int offs[12];
#pragma unroll
    for (int k = 0; k < 12; ++k) {
        const int g = k * 64 + lane;
        const int r = g / 12, j4 = g % 12;
        offs[k] = r * (BN * TT * 4) + j4 * 16;
    }

#define STAGE_CHUNK(tb, buf)                                                   \
    {                                                                          \
        const char* cb = (const char*)emis + ((size_t)(tb) * BN + b) * (TT * 4); \
        _Pragma("unroll")                                                      \
        for (int k = 0; k < 12; ++k) {                                         \
            __builtin_amdgcn_global_load_lds(                                  \
                (const __attribute__((address_space(1))) void*)(cb + offs[k]), \
                (__attribute__((address_space(3))) void*)(&ebuf[buf][k * 256]),\
                16, 0, 0);                                                     \
        }                                                                      \
    }

    // ---- prologue ----
    STAGE_CHUNK(0, 0);
    int tgv = tags[(size_t)lane * BN + b];
    int mkv = mask[(size_t)lane * BN + b];
    const int tag0 = tags[b];

    for (int i = lane; i < TT * TT; i += 64) ltr[i] = trans[i];
    stb[lane] = (lane < TT) ? start_t[lane] : 0.f;
    enb[lane] = (lane < TT) ? end_t[lane] : 0.f;
    __syncthreads();

    // B fragments: B0 (k 0..31), B1 (k 32..63, rows >=48 zero), per col-tile n
    s32x4 B0[3], B1[3];
#pragma unroll
    for (int n = 0; n < 3; ++n) {
#pragma unroll
        for (int kt = 0; kt < 2; ++kt) {
            u16 tmp[8];
#pragma unroll
            for (int e = 0; e < 8; ++e) {
                const int i = kt * 32 + (lane >> 4) * 8 + e;
                const int j = n * 16 + (lane & 15);
                float x = 0.0f;
                if (i < TT) x = fexp2(ltr[i * TT + j] * LOG2E);
                tmp[e] = f2bf(x);
            }
            s32x4 fr;
#pragma unroll
            for (int d = 0; d < 4; ++d)
                fr[d] = (int)((unsigned)tmp[2 * d] | ((unsigned)tmp[2 * d + 1] << 16));
            if (kt == 0) B0[n] = fr; else B1[n] = fr;
        }
    }

    // transpose address constants
    const int addr15 = (lane & 15) * 4;
    int aP0[4], aP1[4];
#pragma unroll
    for (int d = 0; d < 4; ++d) {
        aP0[d] = (((lane >> 4) * 8 + 2 * d) & 63) * 4;
        aP1[d] = ((32 + (lane >> 4) * 8 + 2 * d) & 63) * 4;
    }
    const bool evenlane = ((lane & 1) == 0);

    asm volatile("s_waitcnt vmcnt(0)" ::: "memory");
    __builtin_amdgcn_sched_barrier(0);

    // ---- init state (t=0): r0_j = exp(st_j + e0_j - 6 ln2) in lane-per-tag ----
    const float e00 = ebuf[0][jc];
    const float r0 = jv ? fexp2(fmaf(stb[jc] + e00, LOG2E, -6.0f)) : 0.0f;
    int la = 6;

    // C regs seeded with r0 in q-layout (renorm source)
    f32x4 c0 = {0.f,0.f,0.f,0.f}, c1 = c0, c2 = c0;
    c0[0] = bpermf(addr15, r0);
    c1[0] = bpermf(addr15 + 64, r0);
    c2[0] = bpermf(addr15 + 128, r0);

    // A frags from r0
    s32x4 A0, A1;
    {
        const float qx = __shfl_xor(r0, 1, 64);
        const int pk = cvtpk(evenlane ? r0 : qx, evenlane ? qx : r0);
#pragma unroll
        for (int d = 0; d < 4; ++d) { A0[d] = bperm(aP0[d], pk); A1[d] = bperm(aP1[d], pk); }
    }

    float numpart = (lane == tag0) ? (stb[jc] + e00) : 0.f;
    float numtr = 0.f, numem = 0.f;
    int mcount = 0;
    int carry_tag = tag0;

    STAGE_CHUNK(CH, 1);
    int tgn = tags[((size_t)CH + lane) * BN + b];
    int mkn = mask[((size_t)CH + lane) * BN + b];

    int cur = 0;

#pragma unroll 1
    for (int c = 0; c < NCH; ++c) {
        const int tbase = c * CH;
        const float* ebc = ebuf[cur];

        // ---- chunk-parallel numerator + commit word ----
        const int tmv = (mkv && (tbase + lane) > 0) ? tgv : -1;
        const unsigned long long vmword = __ballot(tmv >= 0);
        int tprev = __shfl_up(tgv, 1, 64);
        if (lane == 0) tprev = carry_tag;
        if (tmv >= 0) {
            numtr += ltr[tprev * TT + tgv];
            numem += ebc[lane * TT + tgv];
        }
        carry_tag = __builtin_amdgcn_readlane(tgv, 63);
        mcount += __popcll(__ballot(mkv != 0));
        la += 6 * (int)__popcll(vmword);

        // ---- 8 groups x 8 serial MFMA steps ----
#pragma unroll 1
        for (int sc = 0; sc < 8; ++sc) {
            // emission multipliers in C-layout for this group (off-chain)
            float emulC[24];
#pragma unroll
            for (int u8 = 0; u8 < 8; ++u8)
#pragma unroll
                for (int n = 0; n < 3; ++n)
                    emulC[u8 * 3 + n] = fexp2(fmaf(
                        ebc[(sc * 8 + u8) * TT + n * 16 + (lane & 15)], LOG2E, -6.0f));

            const unsigned gm = (unsigned)(vmword >> (sc * 8)) & 0xFFu;

#pragma unroll
            for (int u = 0; u < 8; ++u) {
                if ((gm >> u) & 1u) {  // uniform branch
                    float w0 = emulC[u * 3], w1 = emulC[u * 3 + 1], w2 = emulC[u * 3 + 2];
                    if (u == 0) {  // renorm: exact power-of-2 rescale, exact bookkeeping
                        const float q0 = rlane0(c0[0]);
                        const int m = ((__float_as_int(q0) >> 23) & 0xFF) - 127;
                        const float scl = __int_as_float((127 - m) << 23);
                        la += m;
                        w0 *= scl; w1 *= scl; w2 *= scl;
                    }
                    const float q0v = c0[0] * w0;
                    const float q1v = c1[0] * w1;
                    const float q2v = c2[0] * w2;
                    // assemble q into lane-per-tag order (lanes 0..47)
                    const float b1v = bpermf(addr15, q1v);
                    const float b2v = bpermf(addr15, q2v);
                    const float qall = (lane < 16) ? q0v : ((lane < 32) ? b1v : b2v);
                    // pack bf16 pairs in-lane, gather into A fragments
                    const float qx = __shfl_xor(qall, 1, 64);
                    const int pk = cvtpk(evenlane ? qall : qx, evenlane ? qx : qall);
#pragma unroll
                    for (int d = 0; d < 4; ++d) {
                        A0[d] = bperm(aP0[d], pk);
                        A1[d] = bperm(aP1[d], pk);
                    }
                    // q_next = p @ E  (6 MFMA)
                    const f32x4 z = {0.f, 0.f, 0.f, 0.f};
                    c0 = MFMA(A0, B0[0], z); c1 = MFMA(A0, B0[1], z); c2 = MFMA(A0, B0[2], z);
                    c0 = MFMA(A1, B1[0], c0); c1 = MFMA(A1, B1[1], c1); c2 = MFMA(A1, B1[2], c2);
                }
            }
        }

        // ---- chunk boundary ----
        asm volatile("s_waitcnt vmcnt(0)" ::: "memory");
        __builtin_amdgcn_sched_barrier(0);
        cur ^= 1;
        tgv = tgn; mkv = mkn;
        if (c + 2 < NCH) {
            STAGE_CHUNK(tbase + 2 * CH, cur ^ 1);
            tgn = tags[((size_t)(tbase + 2 * CH) + lane) * BN + b];
            mkn = mask[((size_t)(tbase + 2 * CH) + lane) * BN + b];
        }
    }

    // ---- numerator tail ----
    const int last_tag = tags[(size_t)(mcount - 1) * BN + b];  // uniform
    numpart += (lane == last_tag) ? enb[jc] * (float)(lane == last_tag) : 0.f;
    numpart += numtr + numem;

    // ---- denominator from A frags (state r in bf16, rows: lanes l&15==0) ----
    float sp = 0.f;
    const float gA1 = (lane < 32) ? 1.f : 0.f;
#pragma unroll
    for (int d = 0; d < 4; ++d) {
        const int u0 = A0[d];
        const int j0 = (lane >> 4) * 8 + 2 * d;           // 0..31
        sp += __int_as_float((unsigned)u0 << 16) * fexp2(enb[j0] * LOG2E);
        sp += __int_as_float((unsigned)u0 & 0xFFFF0000u) * fexp2(enb[j0 + 1] * LOG2E);
        const int u1 = A1[d];
        const int j1 = (32 + (lane >> 4) * 8 + 2 * d) & 63;  // 32..63 (>=48 gated)
        sp += gA1 * __int_as_float((unsigned)u1 << 16) * fexp2(enb[j1] * LOG2E);
        sp += gA1 * __int_as_float((unsigned)u1 & 0xFFFF0000u) * fexp2(enb[j1 + 1] * LOG2E);
    }
    if ((lane & 15) != 0) sp = 0.f;   // only row-0 lanes carry state
    float se = sp;
#pragma unroll
    for (int d = 1; d < 64; d <<= 1)
        se += __shfl_xor(se, d, 64);
    const float den = (flog2(se) + (float)la) * LN2;

    float num = numpart;
#pragma unroll
    for (int d = 1; d < 64; d <<= 1)
        num += __shfl_xor(num, d, 64);

    if (lane == 0) ws[b] = num - den;
#undef STAGE_CHUNK
}

__global__ __launch_bounds__(256) void reduce_mean(
    const float* __restrict__ ws, float* __restrict__ out)
{
    const int tid = threadIdx.x;
    float v = ws[tid] + ws[tid + 256] + ws[tid + 512] + ws[tid + 768];
#pragma unroll
    for (int d = 1; d < 64; d <<= 1)
        v += __shfl_xor(v, d, 64);
    __shared__ float acc[4];
    if ((tid & 63) == 0) acc[tid >> 6] = v;
    __syncthreads();
    if (tid == 0) out[0] = (acc[0] + acc[1] + acc[2] + acc[3]) * (1.f / 1024.f);
}

extern "C" void kernel_launch(void* const* d_in, const int* in_sizes, int n_in,
                              void* d_out, int out_size, void* d_ws, size_t ws_size,
                              hipStream_t stream)
{
    const float* emis    = (const float*)d_in[0];
    const int*   tags    = (const int*)d_in[1];
    const int*   mask    = (const int*)d_in[2];
    const float* start_t = (const float*)d_in[3];
    const float* end_t   = (const float*)d_in[4];
    const float* trans   = (const float*)d_in[5];
    float* ws  = (float*)d_ws;
    float* out = (float*)d_out;

    crf_fwd<<<dim3(BN), dim3(64), 0, stream>>>(emis, tags, mask, start_t, end_t, trans, ws);
    reduce_mean<<<dim3(1), dim3(256), 0, stream>>>(ws, out);
}